// Round 8
// baseline (1122.320 us; speedup 1.0000x reference)
//
#include <hip/hip_runtime.h>
#include <hip/hip_bf16.h>
#include <cstdio>
#include <cstdint>

#define N_TOK 8192
#define D_DIM 2048
#define H_DIM 2048
#define N_EXP 8
#define TOP_K 2
#define NT_CP (N_TOK * TOP_K)

typedef __attribute__((ext_vector_type(4))) float f32x4;
typedef __attribute__((ext_vector_type(8))) short s16x8;
typedef __attribute__((ext_vector_type(4))) short s16x4;

static constexpr size_t OFF_CNT  = 0;
static constexpr size_t OFF_ROWS = 256;
static constexpr size_t OFF_WTS  = OFF_ROWS + (size_t)(NT_CP + 128) * 4;
static constexpr size_t OFF_XB   = OFF_WTS  + (size_t)(NT_CP + 128) * 4;
static constexpr size_t OFF_ACT  = OFF_XB   + (size_t)N_TOK * D_DIM * 2;
static constexpr size_t OFF_W13T = OFF_ACT  + (size_t)(NT_CP + 128) * H_DIM * 2;
static constexpr size_t OFF_W2T  = OFF_W13T + (size_t)N_EXP * 4096 * (size_t)D_DIM * 2;
static constexpr size_t WS_NEED  = OFF_W2T  + (size_t)N_EXP * (size_t)H_DIM * D_DIM * 2;

__device__ __forceinline__ short f2bf(float f) {
    uint32_t u = __builtin_bit_cast(uint32_t, f);
    uint32_t r = (u + 0x7FFFu + ((u >> 16) & 1u)) >> 16;
    return (short)r;
}

#define GLOAD_LDS16(g, l)                                                                  \
    __builtin_amdgcn_global_load_lds((const __attribute__((address_space(1))) void*)(g),   \
                                     (__attribute__((address_space(3))) void*)(l), 16, 0, 0)

// ---------------- routing: packed slot assignment per expert ----------------
__global__ void routing_kernel(const int* __restrict__ eidx, const float* __restrict__ ew,
                               const int* __restrict__ bspe, int* __restrict__ cnt,
                               int* __restrict__ rows, float* __restrict__ wts) {
    int i = blockIdx.x * blockDim.x + threadIdx.x;
    if (i >= NT_CP) return;
    int e = eidx[i];
    int off = 0;
#pragma unroll
    for (int j = 0; j < N_EXP; ++j) off += (j < e) ? bspe[j] : 0;
    int slot = atomicAdd(&cnt[e], 1);
    rows[off + slot] = i / TOP_K;
    wts[off + slot]  = ew[i];
}

// ---------------- cast x (fp32 -> bf16), vectorized ----------------
__global__ void cast_x_kernel(const float* __restrict__ x, short* __restrict__ xb) {
    int i = blockIdx.x * blockDim.x + threadIdx.x;
    const int total = N_TOK * D_DIM / 4;
    if (i >= total) return;
    f32x4 v = ((const f32x4*)x)[i];
    s16x4 o;
    o.x = f2bf(v.x); o.y = f2bf(v.y); o.z = f2bf(v.z); o.w = f2bf(v.w);
    ((s16x4*)xb)[i] = o;
}

// ---------------- fused transpose+cast (verified round 5) ----------------
__global__ void transpose_cast_fused(const float* __restrict__ w1, const float* __restrict__ w3,
                                     const float* __restrict__ w2, short* __restrict__ w13t,
                                     short* __restrict__ w2t) {
    __shared__ float t[64][65];
    const int slab = blockIdx.z;           // 0..23
    const int mat = slab >> 3, e = slab & 7;
    const float* in = (mat == 0 ? w1 : (mat == 1 ? w3 : w2)) + (size_t)e * D_DIM * H_DIM;
    short* out = (mat == 2) ? (w2t + (size_t)e * D_DIM * H_DIM)
                            : (w13t + (size_t)e * 4096 * D_DIM);
    const int r0 = blockIdx.y * 64, c0 = blockIdx.x * 64;
    const int tid = threadIdx.x;

#pragma unroll
    for (int p = 0; p < 4; ++p) {
        int r = p * 16 + (tid >> 4);
        int c4 = (tid & 15) * 4;
        f32x4 v = *(const f32x4*)&in[(size_t)(r0 + r) * 2048 + c0 + c4];
        t[r][c4 + 0] = v.x; t[r][c4 + 1] = v.y; t[r][c4 + 2] = v.z; t[r][c4 + 3] = v.w;
    }
    __syncthreads();
#pragma unroll
    for (int p = 0; p < 2; ++p) {
        int c = c0 + p * 32 + (tid >> 3);
        int r8 = (tid & 7) * 8;
        s16x8 o;
#pragma unroll
        for (int j = 0; j < 8; ++j) o[j] = f2bf(t[r8 + j][c - c0]);
        int row2 = (mat == 2) ? c : (((c >> 4) << 5) + ((mat == 1) ? 16 : 0) + (c & 15));
        *(s16x8*)&out[(size_t)row2 * 2048 + r0 + r8] = o;
    }
}

// ================= 256x256 grouped GEMM, 8 waves, dbuf + counted vmcnt(8) =================
// MODE 0: A = xb (gathered rows), B = w13t (4096 rows/exp), epi = silu(g)*u -> act (bf16)
// MODE 1: A = act (contiguous),   B = w2t  (2048 rows/exp), epi = atomicAdd(y, acc*wt)
// T2 swizzle: linear gload_lds dest; global src 16B-block = (tid&7)^((tid>>3)&7);
//             ds_read colb = (slot ^ (row&7))*16. T4: vmcnt(8) in loop, 0 only at peel.
template <int MODE>
__launch_bounds__(512, 2)
__global__ void gemm_8p(const short* __restrict__ Aglob, const short* __restrict__ Bglob,
                        const int* __restrict__ rows, const float* __restrict__ wts,
                        const int* __restrict__ bspe, short* __restrict__ act_out,
                        float* __restrict__ y) {
    const int e = blockIdx.z;
    const int cnt_e = bspe[e];
    const int mt = blockIdx.y;
    if (mt * 256 >= cnt_e) return;
    int off_e = 0;
#pragma unroll
    for (int j = 0; j < N_EXP; ++j) off_e += (j < e) ? bspe[j] : 0;
    const int p0 = off_e + mt * 256;
    const int bn0 = blockIdx.x * 256;
    int valid_rows = cnt_e - mt * 256;
    if (valid_rows > 256) valid_rows = 256;

    __shared__ short smem[65536];  // 128 KB: buf b at b*32768 (A 16384 | B 16384 shorts)

    const int tid = threadIdx.x;
    const int lane = tid & 63;
    const int wid = tid >> 6;
    const int wm = (wid >> 2) * 128;   // 2 waves over M
    const int wn = (wid & 3) * 64;     // 4 waves over N

    // ---- staging sources (pre-swizzled 16B block within each 128B row) ----
    const int srow = tid >> 3;                       // 0..63
    const int sblk = (tid & 7) ^ (srow & 7);         // inverse swizzle
    const int NROWS_B = (MODE == 0) ? 4096 : 2048;
    const short* a_src[4];
    const short* b_src[4];
#pragma unroll
    for (int i = 0; i < 4; ++i) {
        int r = i * 64 + srow;
        if (MODE == 0) {
            int tok = (r < valid_rows) ? rows[p0 + r] : rows[p0];
            a_src[i] = Aglob + (size_t)tok * 2048 + sblk * 8;
        } else {
            int rp = (r < valid_rows) ? (p0 + r) : p0;   // clamp: stay in act buffer
            a_src[i] = Aglob + (size_t)rp * 2048 + sblk * 8;
        }
        b_src[i] = Bglob + ((size_t)e * NROWS_B + bn0 + r) * 2048 + sblk * 8;
    }

#define STAGE(buf, k0)                                                        \
    do {                                                                      \
        short* da_ = smem + (buf) * 32768;                                    \
        short* db_ = da_ + 16384;                                             \
        _Pragma("unroll")                                                     \
        for (int i_ = 0; i_ < 4; ++i_) {                                      \
            GLOAD_LDS16(a_src[i_] + (k0), &da_[(i_ * 512 + tid) * 8]);        \
            GLOAD_LDS16(b_src[i_] + (k0), &db_[(i_ * 512 + tid) * 8]);        \
        }                                                                     \
    } while (0)

    f32x4 acc[8][4];
#pragma unroll
    for (int mi = 0; mi < 8; ++mi)
#pragma unroll
        for (int ni = 0; ni < 4; ++ni) acc[mi][ni] = (f32x4){0.f, 0.f, 0.f, 0.f};

#define PHASE(bufbase, mh, nh)                                                             \
    do {                                                                                   \
        const char* pa_ = (const char*)(bufbase);                                          \
        const char* pb_ = pa_ + 32768;                                                     \
        s16x8 af_[4][2], bf_[2][2];                                                        \
        _Pragma("unroll")                                                                  \
        for (int mi_ = 0; mi_ < 4; ++mi_) {                                                \
            int row_ = wm + (mh) * 64 + mi_ * 16 + (lane & 15);                            \
            _Pragma("unroll")                                                              \
            for (int kk_ = 0; kk_ < 2; ++kk_) {                                            \
                int colb_ = ((kk_ * 4 + (lane >> 4)) ^ (row_ & 7)) * 16;                   \
                af_[mi_][kk_] = *(const s16x8*)(pa_ + row_ * 128 + colb_);                 \
            }                                                                              \
        }                                                                                  \
        _Pragma("unroll")                                                                  \
        for (int nj_ = 0; nj_ < 2; ++nj_) {                                                \
            int row_ = wn + (nh) * 32 + nj_ * 16 + (lane & 15);                            \
            _Pragma("unroll")                                                              \
            for (int kk_ = 0; kk_ < 2; ++kk_) {                                            \
                int colb_ = ((kk_ * 4 + (lane >> 4)) ^ (row_ & 7)) * 16;                   \
                bf_[nj_][kk_] = *(const s16x8*)(pb_ + row_ * 128 + colb_);                 \
            }                                                                              \
        }                                                                                  \
        __builtin_amdgcn_s_setprio(1);                                                     \
        _Pragma("unroll")                                                                  \
        for (int kk_ = 0; kk_ < 2; ++kk_)                                                  \
            _Pragma("unroll")                                                              \
            for (int mi_ = 0; mi_ < 4; ++mi_)                                              \
                _Pragma("unroll")                                                          \
                for (int nj_ = 0; nj_ < 2; ++nj_)                                          \
                    acc[(mh) * 4 + mi_][(nh) * 2 + nj_] = __builtin_amdgcn_mfma_f32_16x16x32_bf16( \
                        af_[mi_][kk_], bf_[nj_][kk_], acc[(mh) * 4 + mi_][(nh) * 2 + nj_], 0, 0, 0); \
        __builtin_amdgcn_s_setprio(0);                                                     \
    } while (0)

    // ---- prologue: stage tiles 0 and 1 (16 loads outstanding) ----
    STAGE(0, 0);
    STAGE(1, 64);

    // ---- main loop: tiles 0..30; tile t+1's 8 loads stay in flight (T4) ----
    for (int t = 0; t < 31; ++t) {
        asm volatile("s_waitcnt vmcnt(8)" ::: "memory");   // S(t) fully landed (FIFO)
        __builtin_amdgcn_s_barrier();                      // publish all waves' staging
        const short* bb = smem + (t & 1) * 32768;
        PHASE(bb, 0, 0);
        PHASE(bb, 0, 1);
        PHASE(bb, 1, 0);
        PHASE(bb, 1, 1);
        asm volatile("" ::: "memory");
        __builtin_amdgcn_s_barrier();                      // all reads of buf[t&1] done
        if (t + 2 < 32) STAGE(t & 1, (t + 2) * 64);        // overwrite just-read buffer
    }
    // ---- peeled last tile (31, buf 1): full drain ----
    asm volatile("s_waitcnt vmcnt(0)" ::: "memory");
    __builtin_amdgcn_s_barrier();
    {
        const short* bb = smem + 32768;
        PHASE(bb, 0, 0);
        PHASE(bb, 0, 1);
        PHASE(bb, 1, 0);
        PHASE(bb, 1, 1);
    }

    // ---- epilogues (verbatim structure from verified round-5 kernels) ----
    if (MODE == 0) {
        const int hbase = (bn0 + wn) >> 1;
#pragma unroll
        for (int mi = 0; mi < 8; ++mi) {
#pragma unroll
            for (int j = 0; j < 4; ++j) {
                int row = wm + mi * 16 + (lane >> 4) * 4 + j;
                if (row < valid_rows) {
                    size_t base = (size_t)(p0 + row) * H_DIM + hbase + (lane & 15);
#pragma unroll
                    for (int p = 0; p < 2; ++p) {
                        float g = acc[mi][2 * p][j];
                        float u = acc[mi][2 * p + 1][j];
                        float s = g / (1.0f + __expf(-g));
                        act_out[base + p * 16] = f2bf(s * u);
                    }
                }
            }
        }
    } else {
#pragma unroll
        for (int mi = 0; mi < 8; ++mi) {
#pragma unroll
            for (int j = 0; j < 4; ++j) {
                int row = wm + mi * 16 + (lane >> 4) * 4 + j;
                if (row < valid_rows) {
                    int p = p0 + row;
                    int tok = rows[p];
                    float w = wts[p];
                    float* yb = y + (size_t)tok * D_DIM + bn0 + wn + (lane & 15);
#pragma unroll
                    for (int ni = 0; ni < 4; ++ni)
                        atomicAdd(yb + ni * 16, acc[mi][ni][j] * w);
                }
            }
        }
    }
#undef STAGE
#undef PHASE
}

extern "C" void kernel_launch(void* const* d_in, const int* in_sizes, int n_in,
                              void* d_out, int out_size, void* d_ws, size_t ws_size,
                              hipStream_t stream) {
    const float* x    = (const float*)d_in[0];
    const float* ew   = (const float*)d_in[1];
    const float* w1   = (const float*)d_in[2];
    const float* w2   = (const float*)d_in[3];
    const float* w3   = (const float*)d_in[4];
    const int* eidx   = (const int*)d_in[5];
    const int* bspe   = (const int*)d_in[6];
    float* y          = (float*)d_out;
    char* ws          = (char*)d_ws;

    if (ws_size < WS_NEED) {
        fprintf(stderr, "[kernel] ws too small: have %zu need %zu\n", ws_size, WS_NEED);
        return;
    }

    int*   cnt  = (int*)(ws + OFF_CNT);
    int*   rows = (int*)(ws + OFF_ROWS);
    float* wts  = (float*)(ws + OFF_WTS);
    short* xb   = (short*)(ws + OFF_XB);
    short* act  = (short*)(ws + OFF_ACT);
    short* w13t = (short*)(ws + OFF_W13T);
    short* w2t  = (short*)(ws + OFF_W2T);

    hipMemsetAsync(cnt, 0, 256, stream);
    hipMemsetAsync(y, 0, (size_t)N_TOK * D_DIM * 4, stream);

    routing_kernel<<<NT_CP / 256, 256, 0, stream>>>(eidx, ew, bspe, cnt, rows, wts);
    cast_x_kernel<<<(N_TOK * D_DIM / 4) / 256, 256, 0, stream>>>(x, xb);

    transpose_cast_fused<<<dim3(2048 / 64, 2048 / 64, 24), 256, 0, stream>>>(w1, w3, w2, w13t, w2t);

    gemm_8p<0><<<dim3(4096 / 256, 16, N_EXP), 512, 0, stream>>>(xb, w13t, rows, nullptr, bspe, act, nullptr);
    gemm_8p<1><<<dim3(2048 / 256, 16, N_EXP), 512, 0, stream>>>(act, w2t, rows, wts, bspe, nullptr, y);
}